// Round 2
// baseline (122306.726 us; speedup 1.0000x reference)
//
#include <hip/hip_runtime.h>
#include <stdint.h>

#define BATCH 4096
#define RNN   512
#define SEGS  512

typedef __attribute__((ext_vector_type(8))) short bf16x8;
typedef __attribute__((ext_vector_type(4))) float f32x4;

#define MODE_TANH  0
#define MODE_BASE  1

// cached staging (read-only / prologue data)
#define GLD_LDS16(g, l) \
  __builtin_amdgcn_global_load_lds((const __attribute__((address_space(1))) void*)(g), \
                                   (__attribute__((address_space(3))) void*)(l), 16, 0, 0)
// MALL-coherent staging (cross-block state): aux = SC0|SC1 = 1|16 = 17
#define GLD_LDS16_MALL(g, l) \
  __builtin_amdgcn_global_load_lds((const __attribute__((address_space(1))) void*)(g), \
                                   (__attribute__((address_space(3))) void*)(l), 16, 0, 17)

__device__ __forceinline__ unsigned short f2bf(float f){
  unsigned u = __float_as_uint(f);
  u += 0x7FFF + ((u >> 16) & 1);   // RNE
  return (unsigned short)(u >> 16);
}
__device__ __forceinline__ float bf2f(unsigned short s){
  return __uint_as_float(((unsigned)s) << 16);
}
__device__ __forceinline__ float fsigmoid(float x){ return 1.0f / (1.0f + __expf(-x)); }
__device__ __forceinline__ float ftanh(float x){
  float e = __expf(-2.0f * fabsf(x));
  float t = (1.0f - e) / (1.0f + e);
  return copysignf(t, x);
}

// 16-bit store straight to the MALL (cross-XCD coherence point); never dirties L2.
__device__ __forceinline__ void store_short_mall(unsigned short* p, unsigned short v){
  asm volatile("global_store_short %0, %1, off sc0 sc1" :: "v"(p), "v"((unsigned)v));
}
// 16B MALL-coherent load as 4 agent-scope dwords (compiler tracks the waits).
__device__ __forceinline__ bf16x8 load8_mall(const short* p){
  const unsigned* q = (const unsigned*)p;
  union { unsigned u[4]; bf16x8 v; } r;
  #pragma unroll
  for (int i = 0; i < 4; i++)
    r.u[i] = __hip_atomic_load(q + i, __ATOMIC_RELAXED, __HIP_MEMORY_SCOPE_AGENT);
  return r.v;
}

// ---------------- prep kernels ----------------

__global__ void prep_cvt(const float* __restrict__ x, short* __restrict__ y, int n){
  int i = blockIdx.x * 256 + threadIdx.x;
  if (i < n) y[i] = (short)f2bf(x[i]);
}

// Reorder gate rows: new row 4*j+g  <-  old row g*512+j  (gate order i,f,g,o)
__global__ void prep_reorder(
    const float* __restrict__ W_ih1, const float* __restrict__ W_hh1,
    const float* __restrict__ b_ih1, const float* __restrict__ b_hh1,
    const float* __restrict__ W_ih2, const float* __restrict__ W_hh2,
    const float* __restrict__ b_ih2, const float* __restrict__ b_hh2,
    short* __restrict__ Wr1, short* __restrict__ W1c,
    short* __restrict__ Wr2i, short* __restrict__ Wr2h,
    float* __restrict__ w1r, float* __restrict__ b1r, float* __restrict__ b2r)
{
  int idx = blockIdx.x * 256 + threadIdx.x;   // over 2048*512
  if (idx >= 2048 * 512) return;
  int rn = idx >> 9;        // new row
  int k  = idx & 511;
  int j = rn >> 2, g = rn & 3;
  int ro = g * 512 + j;     // old row
  Wr1 [idx] = (short)f2bf(W_hh1[(size_t)ro * 512 + k]);
  W1c [idx] = (short)f2bf(W_ih1[(size_t)ro * 514 + k]);   // W_ih1 rows are length 514
  Wr2i[idx] = (short)f2bf(W_ih2[(size_t)ro * 512 + k]);
  Wr2h[idx] = (short)f2bf(W_hh2[(size_t)ro * 512 + k]);
  if (k == 0){
    w1r[rn] = W_ih1[(size_t)ro * 514 + 512];  // the "angles" input column
    b1r[rn] = b_ih1[ro] + b_hh1[ro];
    b2r[rn] = b_ih2[ro] + b_hh2[ro];
  }
}

// Pack head weights: Wh[16][512] bf16, rows 0-4 Wmu, 5-9 Wvar, 10-14 Wmix, 15 zero
__global__ void prep_whead(const float* __restrict__ Wmu, const float* __restrict__ Wvar,
                           const float* __restrict__ Wmix, short* __restrict__ Wh){
  int i = blockIdx.x * 256 + threadIdx.x;   // 16*512
  if (i >= 16 * 512) return;
  int n = i >> 9, k = i & 511;
  float v = (n < 5) ? Wmu[n * 512 + k] : (n < 10) ? Wvar[(n - 5) * 512 + k]
          : (n < 15) ? Wmix[(n - 10) * 512 + k] : 0.f;
  Wh[i] = (short)f2bf(v);
}

// ---------------- fused bf16 MFMA GEMM (prologue TANH/BASE only) ----------------
__global__ __launch_bounds__(256) void gemm_fused(
    const short* __restrict__ A1, const short* __restrict__ B1,
    int k1, int N, int mode,
    const float* __restrict__ bias,
    void* __restrict__ outp)
{
  __shared__ __align__(16) short As[8192];
  __shared__ __align__(16) short Bs[8192];

  const int tid  = threadIdx.x;
  const int lane = tid & 63;
  const int wave = tid >> 6;
  const int wm = wave >> 1, wn = wave & 1;
  const int m0 = blockIdx.y * 128, n0 = blockIdx.x * 128;

  int aoff[4], boff[4];
  #pragma unroll
  for (int j = 0; j < 4; j++){
    int c = (wave * 4 + j) * 64 + lane;
    int quad = c & 3, r16 = (c >> 2) & 15, kw = (c >> 6) & 1, g = c >> 7;
    int row = g * 16 + r16, col = kw * 32 + quad * 8;
    aoff[j] = (m0 + row) * 512 + col;
    boff[j] = (n0 + row) * 512 + col;
  }

  f32x4 acc[4][4];
  #pragma unroll
  for (int i = 0; i < 4; i++)
    #pragma unroll
    for (int j = 0; j < 4; j++)
      acc[i][j] = (f32x4){0.f, 0.f, 0.f, 0.f};

  const int nk = k1 >> 6;

  auto stage = [&](int it){
    int kk = it << 6;
    #pragma unroll
    for (int j = 0; j < 4; j++){
      GLD_LDS16(A1 + aoff[j] + kk, (char*)As + (wave * 4 + j) * 1024);
      GLD_LDS16(B1 + boff[j] + kk, (char*)Bs + (wave * 4 + j) * 1024);
    }
  };

  const int fro = ((lane & 15) * 4 + (lane >> 4)) * 8;

  auto compute = [&](){
    #pragma unroll
    for (int kw = 0; kw < 2; ++kw){
      bf16x8 af[4], bfr[4];
      #pragma unroll
      for (int f = 0; f < 4; f++){
        af[f]  = *(const bf16x8*)&As[((wm * 4 + f) * 2 + kw) * 512 + fro];
        bfr[f] = *(const bf16x8*)&Bs[((wn * 4 + f) * 2 + kw) * 512 + fro];
      }
      #pragma unroll
      for (int mf = 0; mf < 4; mf++)
        #pragma unroll
        for (int nf = 0; nf < 4; nf++)
          acc[mf][nf] = __builtin_amdgcn_mfma_f32_16x16x32_bf16(af[mf], bfr[nf], acc[mf][nf], 0, 0, 0);
    }
  };

  stage(0);
  __syncthreads();
  compute();
  __syncthreads();
  for (int it = 1; it < nk; ++it){
    stage(it);
    __syncthreads();
    compute();
    __syncthreads();
  }

  const int lr = (lane >> 4) * 4;
  const int lc = lane & 15;
  unsigned short* out = (unsigned short*)outp;
  #pragma unroll
  for (int mf = 0; mf < 4; mf++)
    #pragma unroll
    for (int nf = 0; nf < 4; nf++)
      #pragma unroll
      for (int r = 0; r < 4; r++){
        int grow = m0 + wm * 64 + mf * 16 + lr + r;
        int gcol = n0 + wn * 64 + nf * 16 + lc;
        float v = acc[mf][nf][r] + bias[gcol];
        out[(size_t)grow * N + gcol] = f2bf(mode == MODE_TANH ? ftanh(v) : v);
      }
}

// ---------------- persistent scan kernel ----------------
// Grid barrier with NO cache-maintenance ops: all cross-block data moves via
// sc0|sc1 (MALL-coherent) accesses, so visibility needs only store-completion,
// which __syncthreads' implicit vmcnt(0) provides for every wave.
__device__ __forceinline__ void gridbar(unsigned* cnt, int G, int& gen, bool& bail){
  __syncthreads();                     // all waves drain vmcnt -> sc1 stores acked at MALL
  if (threadIdx.x == 0){
    gen++;
    __hip_atomic_fetch_add(cnt, 1u, __ATOMIC_RELAXED, __HIP_MEMORY_SCOPE_AGENT);
    if (!bail){
      const unsigned tgt = (unsigned)G * (unsigned)gen;
      unsigned iters = 0;
      while (__hip_atomic_load(cnt, __ATOMIC_RELAXED, __HIP_MEMORY_SCOPE_AGENT) < tgt){
        __builtin_amdgcn_s_sleep(2);
        if (++iters > (1u << 24)) { bail = true; break; }
      }
    }
  }
  __syncthreads();
}

// One 128x128 output tile of one LSTM-cell phase.
// PHASE==1: gates1 = base1 + ang*w1r + h1@Wr1^T (K=512), fused head from h2prev.
// PHASE==2: gates2 = b2r + h1'@Wr2i^T + h2@Wr2h^T (K=1024).
// A-operands are cross-block state -> MALL-coherent staging; B-operands are
// read-only weights -> normal cached staging (L2 stays hot, never invalidated).
// c-state is block-private (fixed tile->block map, blocks never migrate) -> cached.
template<int PHASE>
__device__ __forceinline__ void run_tile(
    int t, int s,
    const short* __restrict__ A1, const short* __restrict__ B1,
    const short* __restrict__ A2, const short* __restrict__ B2,
    const unsigned short* __restrict__ base1, const float* __restrict__ w1r,
    const float* __restrict__ bias2,
    float* __restrict__ cbuf, unsigned short* __restrict__ hout,
    const short* __restrict__ h2prev, const short* __restrict__ Whead,
    const float* __restrict__ bmu, const float* __restrict__ bvar,
    const float* __restrict__ bmix, const float* __restrict__ eps,
    float* __restrict__ fout,
    short* As, short* Bs, float* headP, float* angS)
{
  const int tid  = threadIdx.x;
  const int lane = tid & 63;
  const int wave = tid >> 6;
  const int wm = wave >> 1, wn = wave & 1;
  // XCD-aware swizzle (blocks round-robin across 8 XCDs): XCD x owns bx {2x,2x+1}
  const int bx = ((t & 7) << 1) | ((t >> 3) & 1);
  const int by = t >> 4;
  const int m0 = by * 128, n0 = bx * 128;

  int aoff[4], boff[4];
  #pragma unroll
  for (int j = 0; j < 4; j++){
    int c = (wave * 4 + j) * 64 + lane;
    int quad = c & 3, r16 = (c >> 2) & 15, kw = (c >> 6) & 1, g = c >> 7;
    int row = g * 16 + r16, col = kw * 32 + quad * 8;
    aoff[j] = (m0 + row) * 512 + col;
    boff[j] = (n0 + row) * 512 + col;
  }

  f32x4 acc[4][4];
  #pragma unroll
  for (int i = 0; i < 4; i++)
    #pragma unroll
    for (int j = 0; j < 4; j++)
      acc[i][j] = (f32x4){0.f, 0.f, 0.f, 0.f};

  const int nk = (PHASE == 1) ? 8 : 16;

  auto stage = [&](int it){
    int ko = it << 6;
    const short* Ap; const short* Bp; int kk;
    if (PHASE == 1 || ko < 512){ Ap = A1; Bp = B1; kk = ko; }
    else                       { Ap = A2; Bp = B2; kk = ko - 512; }
    #pragma unroll
    for (int j = 0; j < 4; j++){
      GLD_LDS16_MALL(Ap + aoff[j] + kk, (char*)As + (wave * 4 + j) * 1024);  // state
      GLD_LDS16     (Bp + boff[j] + kk, (char*)Bs + (wave * 4 + j) * 1024);  // weights
    }
  };

  const int fro = ((lane & 15) * 4 + (lane >> 4)) * 8;

  auto compute = [&](){
    #pragma unroll
    for (int kw = 0; kw < 2; ++kw){
      bf16x8 af[4], bfr[4];
      #pragma unroll
      for (int f = 0; f < 4; f++){
        af[f]  = *(const bf16x8*)&As[((wm * 4 + f) * 2 + kw) * 512 + fro];
        bfr[f] = *(const bf16x8*)&Bs[((wn * 4 + f) * 2 + kw) * 512 + fro];
      }
      #pragma unroll
      for (int mf = 0; mf < 4; mf++)
        #pragma unroll
        for (int nf = 0; nf < 4; nf++)
          acc[mf][nf] = __builtin_amdgcn_mfma_f32_16x16x32_bf16(af[mf], bfr[nf], acc[mf][nf], 0, 0, 0);
    }
  };

  stage(0);   // head below overlaps these in-flight loads

  if (PHASE == 1 && s > 0){
    // P[128x16] = h2prev[m0..m0+127] @ Whead^T via MFMA; wave handles 2 row-groups
    const int g0 = wave * 2;
    f32x4 pa0 = {0.f,0.f,0.f,0.f}, pa1 = {0.f,0.f,0.f,0.f};
    const int arow = m0 + g0 * 16 + (lane & 15);
    const int koff = (lane >> 4) * 8;
    #pragma unroll
    for (int k0 = 0; k0 < 512; k0 += 32){
      bf16x8 bfh = *(const bf16x8*)&Whead[(lane & 15) * 512 + k0 + koff];
      bf16x8 a0  = load8_mall(h2prev + (size_t)arow * 512 + k0 + koff);
      bf16x8 a1  = load8_mall(h2prev + (size_t)(arow + 16) * 512 + k0 + koff);
      pa0 = __builtin_amdgcn_mfma_f32_16x16x32_bf16(a0, bfh, pa0, 0, 0, 0);
      pa1 = __builtin_amdgcn_mfma_f32_16x16x32_bf16(a1, bfh, pa1, 0, 0, 0);
    }
    #pragma unroll
    for (int r = 0; r < 4; r++){
      headP[((g0    ) * 16 + (lane >> 4) * 4 + r) * 16 + (lane & 15)] = pa0[r];
      headP[((g0 + 1) * 16 + (lane >> 4) * 4 + r) * 16 + (lane & 15)] = pa1[r];
    }
  }

  __syncthreads();   // drains stage(0) loads + headP stores

  if (PHASE == 1){
    if (s > 0){
      if (tid < 128){
        float p[15];
        #pragma unroll
        for (int k = 0; k < 15; k++) p[k] = headP[tid * 16 + k];
        float l[5], mx = -1e30f;
        #pragma unroll
        for (int k = 0; k < 5; k++){ l[k] = p[10 + k] + bmix[k]; mx = fmaxf(mx, l[k]); }
        float se = 0.f, e[5];
        #pragma unroll
        for (int k = 0; k < 5; k++){ e[k] = __expf(l[k] - mx); se += e[k]; }
        float inv = 1.0f / se, mu = 0.f, sg = 0.f;
        #pragma unroll
        for (int k = 0; k < 5; k++){
          float rho = e[k] * inv;
          mu += rho * (p[k] + bmu[k]);
          sg += rho * __expf(p[5 + k] + bvar[k]);
        }
        float a = ftanh(mu + sg * eps[(size_t)(s - 1) * BATCH + m0 + tid]);
        angS[tid] = a;
        if (bx == 0){
          size_t o = ((size_t)(m0 + tid) * SEGS + (s - 1)) * 2;
          fout[o] = a; fout[o + 1] = 0.0f;
        }
      }
    } else if (tid < 128) angS[tid] = 0.f;
  }

  compute();          // iteration 0
  __syncthreads();

  for (int it = 1; it < nk; ++it){
    stage(it);
    __syncthreads();
    compute();
    __syncthreads();
  }

  const int lr = (lane >> 4) * 4;
  const int lc = lane & 15;
  const int q = lane & 3;
  #pragma unroll
  for (int mf = 0; mf < 4; mf++)
    #pragma unroll
    for (int nf = 0; nf < 4; nf++)
      #pragma unroll
      for (int r = 0; r < 4; r++){
        int grow = m0 + wm * 64 + mf * 16 + lr + r;
        int gcol = n0 + wn * 64 + nf * 16 + lc;
        float v = acc[mf][nf][r];
        if (PHASE == 1)
          v += bf2f(base1[(size_t)grow * 2048 + gcol]) + angS[grow - m0] * w1r[gcol];
        else
          v += bias2[gcol];
        float x1 = __shfl_xor(v, 1);
        float x2 = __shfl_xor(v, 2);
        float x3 = __shfl_xor(v, 3);
        if (q == 0){
          int j = gcol >> 2;
          size_t ci = (size_t)grow * 512 + j;
          float co = cbuf[ci];                       // block-private: cached
          float cn = fsigmoid(x1) * co + fsigmoid(v) * ftanh(x2);
          float hn = fsigmoid(x3) * ftanh(cn);
          cbuf[ci] = cn;
          store_short_mall(&hout[ci], f2bf(hn));     // cross-block: MALL
        }
      }
}

__global__ __launch_bounds__(256) void lstm_scan(
    const short* __restrict__ Wr1, const short* __restrict__ Wr2i, const short* __restrict__ Wr2h,
    const unsigned short* __restrict__ base1,
    const float* __restrict__ w1r, const float* __restrict__ b2r,
    float* __restrict__ c1, float* __restrict__ c2,
    short* __restrict__ h1A, short* __restrict__ h1B,
    short* __restrict__ h2A, short* __restrict__ h2B,
    const short* __restrict__ Whead,
    const float* __restrict__ bmu, const float* __restrict__ bvar, const float* __restrict__ bmix,
    const float* __restrict__ eps, float* __restrict__ fout,
    unsigned* __restrict__ barcnt)
{
  __shared__ __align__(16) short As[8192];
  __shared__ __align__(16) short Bs[8192];
  __shared__ __align__(16) float headP[128 * 16];
  __shared__ float angS[128];

  const int bid = blockIdx.x;
  const int G   = gridDim.x;
  int gen = 0;
  bool bail = false;

  for (int s = 0; s < SEGS; ++s){
    const short* h1in  = (s & 1) ? h1B : h1A;
    short*       h1out = (s & 1) ? h1A : h1B;
    const short* h2in  = (s & 1) ? h2B : h2A;
    short*       h2out = (s & 1) ? h2A : h2B;

    // phase 1: fused head(s-1) + cell1 -> h1out, c1
    for (int t = bid; t < 512; t += G)
      run_tile<1>(t, s, h1in, Wr1, nullptr, nullptr, base1, w1r, nullptr,
                  c1, (unsigned short*)h1out, h2in, Whead, bmu, bvar, bmix,
                  eps, fout, As, Bs, headP, angS);
    gridbar(barcnt, G, gen, bail);

    // phase 2: cell2 -> h2out, c2
    for (int t = bid; t < 512; t += G)
      run_tile<2>(t, s, h1out, Wr2i, h2in, Wr2h, nullptr, nullptr, b2r,
                  c2, (unsigned short*)h2out, nullptr, nullptr, nullptr, nullptr,
                  nullptr, nullptr, fout, As, Bs, headP, angS);
    gridbar(barcnt, G, gen, bail);
  }
}

// ---------------- head (tail step only) ----------------
__global__ __launch_bounds__(256) void head_step(
    const short* __restrict__ h2,
    const float* __restrict__ Wmu,  const float* __restrict__ bmu,
    const float* __restrict__ Wvar, const float* __restrict__ bvar,
    const float* __restrict__ Wmix, const float* __restrict__ bmix,
    const float* __restrict__ eps,  float* __restrict__ ang,
    float* __restrict__ out, int s)
{
  const int lane = threadIdx.x & 63;
  const int wave = threadIdx.x >> 6;
  const int row = blockIdx.x * 4 + wave;

  uint4 hv = *(const uint4*)&h2[(size_t)row * 512 + lane * 8];
  const unsigned short* hs = (const unsigned short*)&hv;
  float h[8];
  #pragma unroll
  for (int j = 0; j < 8; j++) h[j] = bf2f(hs[j]);

  float p[15];
  #pragma unroll
  for (int k = 0; k < 5; k++){
    const float4* wm4 = (const float4*)(Wmu  + (size_t)k * 512 + lane * 8);
    const float4* wv4 = (const float4*)(Wvar + (size_t)k * 512 + lane * 8);
    const float4* wx4 = (const float4*)(Wmix + (size_t)k * 512 + lane * 8);
    float4 a0 = wm4[0], a1 = wm4[1];
    float4 v0 = wv4[0], v1 = wv4[1];
    float4 x0 = wx4[0], x1 = wx4[1];
    p[k]      = h[0]*a0.x + h[1]*a0.y + h[2]*a0.z + h[3]*a0.w + h[4]*a1.x + h[5]*a1.y + h[6]*a1.z + h[7]*a1.w;
    p[5 + k]  = h[0]*v0.x + h[1]*v0.y + h[2]*v0.z + h[3]*v0.w + h[4]*v1.x + h[5]*v1.y + h[6]*v1.z + h[7]*v1.w;
    p[10 + k] = h[0]*x0.x + h[1]*x0.y + h[2]*x0.z + h[3]*x0.w + h[4]*x1.x + h[5]*x1.y + h[6]*x1.z + h[7]*x1.w;
  }
  #pragma unroll
  for (int k = 0; k < 15; k++){
    #pragma unroll
    for (int off = 1; off < 64; off <<= 1)
      p[k] += __shfl_xor(p[k], off);
  }
  if (lane == 0){
    float l[5], mx = -1e30f;
    #pragma unroll
    for (int k = 0; k < 5; k++){ l[k] = p[10 + k] + bmix[k]; mx = fmaxf(mx, l[k]); }
    float se = 0.f, e[5];
    #pragma unroll
    for (int k = 0; k < 5; k++){ e[k] = __expf(l[k] - mx); se += e[k]; }
    float inv = 1.0f / se, mu = 0.f, sg = 0.f;
    #pragma unroll
    for (int k = 0; k < 5; k++){
      float rho = e[k] * inv;
      mu += rho * (p[k] + bmu[k]);
      sg += rho * __expf(p[5 + k] + bvar[k]);
    }
    float a = ftanh(mu + sg * eps[(size_t)s * BATCH + row]);
    ang[row] = a;
    size_t o = ((size_t)row * SEGS + s) * 2;
    out[o]     = a;
    out[o + 1] = 0.0f;
  }
}

// ---------------- launch ----------------

extern "C" void kernel_launch(void* const* d_in, const int* in_sizes, int n_in,
                              void* d_out, int out_size, void* d_ws, size_t ws_size,
                              hipStream_t stream)
{
  const float* latent   = (const float*)d_in[0];
  const float* W_unpack = (const float*)d_in[1];
  const float* b_unpack = (const float*)d_in[2];
  const float* W_ih1    = (const float*)d_in[3];
  const float* W_hh1    = (const float*)d_in[4];
  const float* b_ih1    = (const float*)d_in[5];
  const float* b_hh1    = (const float*)d_in[6];
  const float* W_ih2    = (const float*)d_in[7];
  const float* W_hh2    = (const float*)d_in[8];
  const float* b_ih2    = (const float*)d_in[9];
  const float* b_hh2    = (const float*)d_in[10];
  const float* W_mu     = (const float*)d_in[11];
  const float* b_mu     = (const float*)d_in[12];
  const float* W_var    = (const float*)d_in[13];
  const float* b_var    = (const float*)d_in[14];
  const float* W_mix    = (const float*)d_in[15];
  const float* b_mix    = (const float*)d_in[16];
  const float* eps      = (const float*)d_in[17];
  float* out = (float*)d_out;

  char* p = (char*)d_ws;
  auto alloc = [&](size_t b) -> void* {
    void* r = (void*)p;
    p += (b + 255) & ~(size_t)255;
    return r;
  };
  short* latb  = (short*)alloc((size_t)BATCH * 512 * 2);
  short* Wub   = (short*)alloc((size_t)512 * 512 * 2);
  short* idea  = (short*)alloc((size_t)BATCH * 512 * 2);
  unsigned short* base1 = (unsigned short*)alloc((size_t)BATCH * 2048 * 2);
  short* Wr1   = (short*)alloc((size_t)2048 * 512 * 2);
  short* W1c   = (short*)alloc((size_t)2048 * 512 * 2);
  short* Wr2i  = (short*)alloc((size_t)2048 * 512 * 2);
  short* Wr2h  = (short*)alloc((size_t)2048 * 512 * 2);
  short* Whead = (short*)alloc((size_t)16 * 512 * 2);
  float* w1r   = (float*)alloc(2048 * 4);
  float* b1r   = (float*)alloc(2048 * 4);
  float* b2r   = (float*)alloc(2048 * 4);
  short* h1a   = (short*)alloc((size_t)BATCH * 512 * 2);
  short* h1b   = (short*)alloc((size_t)BATCH * 512 * 2);
  short* h2a   = (short*)alloc((size_t)BATCH * 512 * 2);
  short* h2b   = (short*)alloc((size_t)BATCH * 512 * 2);
  float* c1    = (float*)alloc((size_t)BATCH * 512 * 4);
  float* c2    = (float*)alloc((size_t)BATCH * 512 * 4);
  float* ang   = (float*)alloc(BATCH * 4);
  unsigned* barcnt = (unsigned*)alloc(256);

  // Persistent grid size: all blocks must be co-resident (self-sized from the
  // runtime's occupancy calc so register/LDS drift can't deadlock the barrier).
  static int g_G = 0;
  if (g_G == 0){
    int occ = 0, ncu = 256, dev = 0;
    if (hipOccupancyMaxActiveBlocksPerMultiprocessor(&occ, lstm_scan, 256, 0) != hipSuccess || occ < 1)
      occ = 1;
    hipDeviceProp_t prop;
    if (hipGetDevice(&dev) == hipSuccess && hipGetDeviceProperties(&prop, dev) == hipSuccess)
      ncu = prop.multiProcessorCount;
    long g = (long)occ * (long)ncu;
    g_G = (g > 512) ? 512 : (int)g;
    if (g_G < 1) g_G = 256;
  }

  hipMemsetAsync(h1a, 0, (size_t)BATCH * 512 * 2, stream);
  hipMemsetAsync(h2a, 0, (size_t)BATCH * 512 * 2, stream);
  hipMemsetAsync(c1, 0, (size_t)BATCH * 512 * 4, stream);
  hipMemsetAsync(c2, 0, (size_t)BATCH * 512 * 4, stream);
  hipMemsetAsync(barcnt, 0, 256, stream);

  prep_cvt<<<(BATCH * 512) / 256, 256, 0, stream>>>(latent, latb, BATCH * 512);
  prep_cvt<<<(512 * 512) / 256, 256, 0, stream>>>(W_unpack, Wub, 512 * 512);
  prep_reorder<<<(2048 * 512) / 256, 256, 0, stream>>>(
      W_ih1, W_hh1, b_ih1, b_hh1, W_ih2, W_hh2, b_ih2, b_hh2,
      Wr1, W1c, Wr2i, Wr2h, w1r, b1r, b2r);
  prep_whead<<<32, 256, 0, stream>>>(W_mu, W_var, W_mix, Whead);

  dim3 blk(256);
  // idea = tanh(latent @ W_unpack^T + b_unpack)  [bf16]
  gemm_fused<<<dim3(4, 32), blk, 0, stream>>>(
      latb, Wub, 512, 512, MODE_TANH, b_unpack, (void*)idea);
  // base1 = idea @ W1c^T + (b_ih1 + b_hh1)   [bf16, gate-interleaved cols]
  gemm_fused<<<dim3(16, 32), blk, 0, stream>>>(
      idea, W1c, 512, 2048, MODE_BASE, b1r, (void*)base1);

  // whole 512-step scan in one persistent kernel (2 grid barriers per step)
  lstm_scan<<<g_G, blk, 0, stream>>>(
      Wr1, Wr2i, Wr2h, base1, w1r, b2r, c1, c2,
      h1a, h1b, h2a, h2b, Whead, b_mu, b_var, b_mix, eps, out, barcnt);

  // final output column s=511 (final h2 lives in h2a after 512 steps)
  head_step<<<BATCH / 4, 256, 0, stream>>>(
      h2a, W_mu, b_mu, W_var, b_var, W_mix, b_mix, eps, ang, out, SEGS - 1);
}

// Round 6
// 113144.409 us; speedup vs baseline: 1.0810x; 1.0810x over previous
//
#include <hip/hip_runtime.h>
#include <stdint.h>

#define BATCH 4096
#define RNN   512
#define SEGS  512

typedef __attribute__((ext_vector_type(8))) short bf16x8;
typedef __attribute__((ext_vector_type(4))) float f32x4;

#define MODE_TANH  0
#define MODE_BASE  1

// cached staging (prologue GEMM only)
#define GLD_LDS16(g, l) \
  __builtin_amdgcn_global_load_lds((const __attribute__((address_space(1))) void*)(g), \
                                   (__attribute__((address_space(3))) void*)(l), 16, 0, 0)

__device__ __forceinline__ unsigned short f2bf(float f){
  unsigned u = __float_as_uint(f);
  u += 0x7FFF + ((u >> 16) & 1);   // RNE
  return (unsigned short)(u >> 16);
}
__device__ __forceinline__ float bf2f(unsigned short s){
  return __uint_as_float(((unsigned)s) << 16);
}
__device__ __forceinline__ float fsigmoid(float x){ return 1.0f / (1.0f + __expf(-x)); }
__device__ __forceinline__ float ftanh(float x){
  float e = __expf(-2.0f * fabsf(x));
  float t = (1.0f - e) / (1.0f + e);
  return copysignf(t, x);
}

// ---------------- prep kernels ----------------

__global__ void prep_cvt(const float* __restrict__ x, short* __restrict__ y, int n){
  int i = blockIdx.x * 256 + threadIdx.x;
  if (i < n) y[i] = (short)f2bf(x[i]);
}

// Reorder gate rows: new row 4*j+g  <-  old row g*512+j  (gate order i,f,g,o)
__global__ void prep_reorder(
    const float* __restrict__ W_ih1, const float* __restrict__ W_hh1,
    const float* __restrict__ b_ih1, const float* __restrict__ b_hh1,
    const float* __restrict__ W_ih2, const float* __restrict__ W_hh2,
    const float* __restrict__ b_ih2, const float* __restrict__ b_hh2,
    short* __restrict__ Wr1, short* __restrict__ W1c,
    short* __restrict__ Wr2i, short* __restrict__ Wr2h,
    float* __restrict__ w1r, float* __restrict__ b1r, float* __restrict__ b2r)
{
  int idx = blockIdx.x * 256 + threadIdx.x;   // over 2048*512
  if (idx >= 2048 * 512) return;
  int rn = idx >> 9;        // new row
  int k  = idx & 511;
  int j = rn >> 2, g = rn & 3;
  int ro = g * 512 + j;     // old row
  Wr1 [idx] = (short)f2bf(W_hh1[(size_t)ro * 512 + k]);
  W1c [idx] = (short)f2bf(W_ih1[(size_t)ro * 514 + k]);   // W_ih1 rows are length 514
  Wr2i[idx] = (short)f2bf(W_ih2[(size_t)ro * 512 + k]);
  Wr2h[idx] = (short)f2bf(W_hh2[(size_t)ro * 512 + k]);
  if (k == 0){
    w1r[rn] = W_ih1[(size_t)ro * 514 + 512];  // the "angles" input column
    b1r[rn] = b_ih1[ro] + b_hh1[ro];
    b2r[rn] = b_ih2[ro] + b_hh2[ro];
  }
}

// Pack head weights: Wh[16][512] bf16, rows 0-4 Wmu, 5-9 Wvar, 10-14 Wmix, 15 zero
__global__ void prep_whead(const float* __restrict__ Wmu, const float* __restrict__ Wvar,
                           const float* __restrict__ Wmix, short* __restrict__ Wh){
  int i = blockIdx.x * 256 + threadIdx.x;   // 16*512
  if (i >= 16 * 512) return;
  int n = i >> 9, k = i & 511;
  float v = (n < 5) ? Wmu[n * 512 + k] : (n < 10) ? Wvar[(n - 5) * 512 + k]
          : (n < 15) ? Wmix[(n - 10) * 512 + k] : 0.f;
  Wh[i] = (short)f2bf(v);
}

// ---------------- fused bf16 MFMA GEMM (prologue TANH/BASE only) ----------------
__global__ __launch_bounds__(256) void gemm_fused(
    const short* __restrict__ A1, const short* __restrict__ B1,
    int k1, int N, int mode,
    const float* __restrict__ bias,
    void* __restrict__ outp)
{
  __shared__ __align__(16) short As[8192];
  __shared__ __align__(16) short Bs[8192];

  const int tid  = threadIdx.x;
  const int lane = tid & 63;
  const int wave = tid >> 6;
  const int wm = wave >> 1, wn = wave & 1;
  const int m0 = blockIdx.y * 128, n0 = blockIdx.x * 128;

  int aoff[4], boff[4];
  #pragma unroll
  for (int j = 0; j < 4; j++){
    int c = (wave * 4 + j) * 64 + lane;
    int quad = c & 3, r16 = (c >> 2) & 15, kw = (c >> 6) & 1, g = c >> 7;
    int row = g * 16 + r16, col = kw * 32 + quad * 8;
    aoff[j] = (m0 + row) * 512 + col;
    boff[j] = (n0 + row) * 512 + col;
  }

  f32x4 acc[4][4];
  #pragma unroll
  for (int i = 0; i < 4; i++)
    #pragma unroll
    for (int j = 0; j < 4; j++)
      acc[i][j] = (f32x4){0.f, 0.f, 0.f, 0.f};

  const int nk = k1 >> 6;

  auto stage = [&](int it){
    int kk = it << 6;
    #pragma unroll
    for (int j = 0; j < 4; j++){
      GLD_LDS16(A1 + aoff[j] + kk, (char*)As + (wave * 4 + j) * 1024);
      GLD_LDS16(B1 + boff[j] + kk, (char*)Bs + (wave * 4 + j) * 1024);
    }
  };

  const int fro = ((lane & 15) * 4 + (lane >> 4)) * 8;

  auto compute = [&](){
    #pragma unroll
    for (int kw = 0; kw < 2; ++kw){
      bf16x8 af[4], bfr[4];
      #pragma unroll
      for (int f = 0; f < 4; f++){
        af[f]  = *(const bf16x8*)&As[((wm * 4 + f) * 2 + kw) * 512 + fro];
        bfr[f] = *(const bf16x8*)&Bs[((wn * 4 + f) * 2 + kw) * 512 + fro];
      }
      #pragma unroll
      for (int mf = 0; mf < 4; mf++)
        #pragma unroll
        for (int nf = 0; nf < 4; nf++)
          acc[mf][nf] = __builtin_amdgcn_mfma_f32_16x16x32_bf16(af[mf], bfr[nf], acc[mf][nf], 0, 0, 0);
    }
  };

  stage(0);
  __syncthreads();
  compute();
  __syncthreads();
  for (int it = 1; it < nk; ++it){
    stage(it);
    __syncthreads();
    compute();
    __syncthreads();
  }

  const int lr = (lane >> 4) * 4;
  const int lc = lane & 15;
  unsigned short* out = (unsigned short*)outp;
  #pragma unroll
  for (int mf = 0; mf < 4; mf++)
    #pragma unroll
    for (int nf = 0; nf < 4; nf++)
      #pragma unroll
      for (int r = 0; r < 4; r++){
        int grow = m0 + wm * 64 + mf * 16 + lr + r;
        int gcol = n0 + wn * 64 + nf * 16 + lc;
        float v = acc[mf][nf][r] + bias[gcol];
        out[(size_t)grow * N + gcol] = f2bf(mode == MODE_TANH ? ftanh(v) : v);
      }
}

// ---------------- row-local persistent LSTM scan ----------------
// Batch rows are independent: block b owns rows [16b, 16b+16) and runs the
// ENTIRE 512-step recurrence privately. No grid barriers, no cross-block
// coherence, no placement assumptions. h-state in LDS (double-buffered),
// c-state in registers, weights streamed from L2/MALL as direct B-fragments.
//
// MFMA operand pattern (proven by the R0/R2 head path):
//   A-frag: h[row=lane&15][k0 + (lane>>4)*8 .. +8]      (LDS, XOR-swizzled)
//   B-frag: W[col=cb+nf*16+(lane&15)][k0+(lane>>4)*8]    (global row-major)
//   C:      row=(lane>>4)*4+r, col=lane&15
__global__ __launch_bounds__(512) void lstm_block(
    const short* __restrict__ Wr1, const short* __restrict__ Wr2i, const short* __restrict__ Wr2h,
    const unsigned short* __restrict__ base1,
    const float* __restrict__ w1r, const float* __restrict__ b2r,
    const short* __restrict__ Whead,
    const float* __restrict__ bmu, const float* __restrict__ bvar, const float* __restrict__ bmix,
    const float* __restrict__ eps, float* __restrict__ fout)
{
  __shared__ __align__(16) short hs[4][8192];  // h1A, h1B, h2A, h2B : [16][512] bf16
  __shared__ float P[16 * 16];
  __shared__ float angS[16];

  const int tid  = threadIdx.x;
  const int lane = tid & 63;
  const int wave = tid >> 6;            // 0..7
  const int r0   = blockIdx.x * 16;     // global row base
  const int lc   = lane & 15;
  const int lr   = (lane >> 4) * 4;
  const int q    = lane & 3;
  const int t4   = (lane >> 2) & 3;
  const int koff = (lane >> 4) * 8;
  const int arow = lane & 15;

  for (int i = tid; i < 4 * 8192; i += 512) ((short*)hs)[i] = 0;
  if (tid < 16) angS[tid] = 0.f;
  float c1r[16], c2r[16];
  #pragma unroll
  for (int i = 0; i < 16; i++){ c1r[i] = 0.f; c2r[i] = 0.f; }
  __syncthreads();

  // swizzled LDS A-frag read: row=arow, elems k0+koff..+8 (16B, XOR keeps alignment)
  auto ldA = [&](const short* h, int k0) -> bf16x8 {
    int a = (arow << 10) | ((k0 + koff) << 1);
    a ^= (arow & 7) << 4;
    return *(const bf16x8*)((const char*)h + a);
  };

  for (int s = 0; s < SEGS; ++s){
    const short* h1i = hs[s & 1];
    short*       h1o = hs[(s & 1) ^ 1];
    const short* h2i = hs[2 + (s & 1)];
    short*       h2o = hs[2 + ((s & 1) ^ 1)];

    // ---- cell1: gates1 = base1 + ang*w1r + h1 @ Wr1^T  (K=512) ----
    #pragma unroll
    for (int ch = 0; ch < 2; ++ch){
      const int cb = wave * 256 + ch * 128;
      f32x4 acc[8];
      #pragma unroll
      for (int nf = 0; nf < 8; ++nf) acc[nf] = (f32x4){0.f, 0.f, 0.f, 0.f};
      const size_t bb = (size_t)(cb + lc) * 512 + koff;
      #pragma unroll 4
      for (int k0 = 0; k0 < 512; k0 += 32){
        bf16x8 a = ldA(h1i, k0);
        #pragma unroll
        for (int nf = 0; nf < 8; ++nf){
          bf16x8 b = *(const bf16x8*)&Wr1[bb + (size_t)nf * 8192 + k0];
          acc[nf] = __builtin_amdgcn_mfma_f32_16x16x32_bf16(a, b, acc[nf], 0, 0, 0);
        }
      }
      #pragma unroll
      for (int nf = 0; nf < 8; ++nf){
        const int gcol = cb + nf * 16 + lc;
        const float w1 = w1r[gcol];
        float vq = 0.f, x1q = 0.f, x2q = 0.f, x3q = 0.f;
        #pragma unroll
        for (int r = 0; r < 4; ++r){
          float v = acc[nf][r] + bf2f(base1[(size_t)(r0 + lr + r) * 2048 + gcol])
                  + angS[lr + r] * w1;
          float x1 = __shfl_xor(v, 1);
          float x2 = __shfl_xor(v, 2);
          float x3 = __shfl_xor(v, 3);
          if (r == q){ vq = v; x1q = x1; x2q = x2; x3q = x3; }
        }
        float gi = (q == 0) ? vq  : (q == 1) ? x1q : (q == 2) ? x2q : x3q;
        float gf = (q == 0) ? x1q : (q == 1) ? vq  : (q == 2) ? x3q : x2q;
        float gg = (q == 0) ? x2q : (q == 1) ? x3q : (q == 2) ? vq  : x1q;
        float go = (q == 0) ? x3q : (q == 1) ? x2q : (q == 2) ? x1q : vq;
        const int ci = ch * 8 + nf;
        float cn = fsigmoid(gf) * c1r[ci] + fsigmoid(gi) * ftanh(gg);
        float hn = fsigmoid(go) * ftanh(cn);
        c1r[ci] = cn;
        const int row = lr + q;
        const int j   = ((cb + nf * 16) >> 2) + t4;
        int wb = ((row << 10) | (j << 1)) ^ ((row & 7) << 4);
        *(unsigned short*)((char*)h1o + wb) = f2bf(hn);
      }
    }
    __syncthreads();   // h1o complete

    // ---- cell2: gates2 = b2r + h1' @ W2i^T + h2 @ W2h^T  (K=512+512) ----
    #pragma unroll
    for (int ch = 0; ch < 2; ++ch){
      const int cb = wave * 256 + ch * 128;
      f32x4 acc[8];
      #pragma unroll
      for (int nf = 0; nf < 8; ++nf) acc[nf] = (f32x4){0.f, 0.f, 0.f, 0.f};
      const size_t bb = (size_t)(cb + lc) * 512 + koff;
      #pragma unroll 4
      for (int k0 = 0; k0 < 512; k0 += 32){
        bf16x8 a = ldA(h1o, k0);
        #pragma unroll
        for (int nf = 0; nf < 8; ++nf){
          bf16x8 b = *(const bf16x8*)&Wr2i[bb + (size_t)nf * 8192 + k0];
          acc[nf] = __builtin_amdgcn_mfma_f32_16x16x32_bf16(a, b, acc[nf], 0, 0, 0);
        }
      }
      #pragma unroll 4
      for (int k0 = 0; k0 < 512; k0 += 32){
        bf16x8 a = ldA(h2i, k0);
        #pragma unroll
        for (int nf = 0; nf < 8; ++nf){
          bf16x8 b = *(const bf16x8*)&Wr2h[bb + (size_t)nf * 8192 + k0];
          acc[nf] = __builtin_amdgcn_mfma_f32_16x16x32_bf16(a, b, acc[nf], 0, 0, 0);
        }
      }
      #pragma unroll
      for (int nf = 0; nf < 8; ++nf){
        const int gcol = cb + nf * 16 + lc;
        float vq = 0.f, x1q = 0.f, x2q = 0.f, x3q = 0.f;
        #pragma unroll
        for (int r = 0; r < 4; ++r){
          float v = acc[nf][r] + b2r[gcol];
          float x1 = __shfl_xor(v, 1);
          float x2 = __shfl_xor(v, 2);
          float x3 = __shfl_xor(v, 3);
          if (r == q){ vq = v; x1q = x1; x2q = x2; x3q = x3; }
        }
        float gi = (q == 0) ? vq  : (q == 1) ? x1q : (q == 2) ? x2q : x3q;
        float gf = (q == 0) ? x1q : (q == 1) ? vq  : (q == 2) ? x3q : x2q;
        float gg = (q == 0) ? x2q : (q == 1) ? x3q : (q == 2) ? vq  : x1q;
        float go = (q == 0) ? x3q : (q == 1) ? x2q : (q == 2) ? x1q : vq;
        const int ci = ch * 8 + nf;
        float cn = fsigmoid(gf) * c2r[ci] + fsigmoid(gi) * ftanh(gg);
        float hn = fsigmoid(go) * ftanh(cn);
        c2r[ci] = cn;
        const int row = lr + q;
        const int j   = ((cb + nf * 16) >> 2) + t4;
        int wb = ((row << 10) | (j << 1)) ^ ((row & 7) << 4);
        *(unsigned short*)((char*)h2o + wb) = f2bf(hn);
      }
    }
    __syncthreads();   // h2o complete

    // ---- head: P = h2' @ Whead^T, then mixture + rsample + tanh ----
    if (wave == 0){
      f32x4 pa = (f32x4){0.f, 0.f, 0.f, 0.f};
      #pragma unroll 4
      for (int k0 = 0; k0 < 512; k0 += 32){
        bf16x8 a = ldA(h2o, k0);
        bf16x8 b = *(const bf16x8*)&Whead[(size_t)lc * 512 + k0 + koff];
        pa = __builtin_amdgcn_mfma_f32_16x16x32_bf16(a, b, pa, 0, 0, 0);
      }
      #pragma unroll
      for (int r = 0; r < 4; ++r) P[(lr + r) * 16 + lc] = pa[r];
    }
    __syncthreads();   // P visible

    if (wave == 0 && lane < 16){
      float p[15];
      #pragma unroll
      for (int k = 0; k < 15; k++) p[k] = P[lane * 16 + k];
      float l[5], mx = -1e30f;
      #pragma unroll
      for (int k = 0; k < 5; k++){ l[k] = p[10 + k] + bmix[k]; mx = fmaxf(mx, l[k]); }
      float se = 0.f, e[5];
      #pragma unroll
      for (int k = 0; k < 5; k++){ e[k] = __expf(l[k] - mx); se += e[k]; }
      float inv = 1.0f / se, mu = 0.f, sg = 0.f;
      #pragma unroll
      for (int k = 0; k < 5; k++){
        float rho = e[k] * inv;
        mu += rho * (p[k] + bmu[k]);
        sg += rho * __expf(p[5 + k] + bvar[k]);
      }
      float a = ftanh(mu + sg * eps[(size_t)s * BATCH + r0 + lane]);
      angS[lane] = a;
      size_t o = ((size_t)(r0 + lane) * SEGS + s) * 2;
      fout[o] = a; fout[o + 1] = 0.0f;
    }
    __syncthreads();   // angS ready for next step
  }
}

// ---------------- launch ----------------

extern "C" void kernel_launch(void* const* d_in, const int* in_sizes, int n_in,
                              void* d_out, int out_size, void* d_ws, size_t ws_size,
                              hipStream_t stream)
{
  const float* latent   = (const float*)d_in[0];
  const float* W_unpack = (const float*)d_in[1];
  const float* b_unpack = (const float*)d_in[2];
  const float* W_ih1    = (const float*)d_in[3];
  const float* W_hh1    = (const float*)d_in[4];
  const float* b_ih1    = (const float*)d_in[5];
  const float* b_hh1    = (const float*)d_in[6];
  const float* W_ih2    = (const float*)d_in[7];
  const float* W_hh2    = (const float*)d_in[8];
  const float* b_ih2    = (const float*)d_in[9];
  const float* b_hh2    = (const float*)d_in[10];
  const float* W_mu     = (const float*)d_in[11];
  const float* b_mu     = (const float*)d_in[12];
  const float* W_var    = (const float*)d_in[13];
  const float* b_var    = (const float*)d_in[14];
  const float* W_mix    = (const float*)d_in[15];
  const float* b_mix    = (const float*)d_in[16];
  const float* eps      = (const float*)d_in[17];
  float* out = (float*)d_out;

  char* p = (char*)d_ws;
  auto alloc = [&](size_t b) -> void* {
    void* r = (void*)p;
    p += (b + 255) & ~(size_t)255;
    return r;
  };
  short* latb  = (short*)alloc((size_t)BATCH * 512 * 2);
  short* Wub   = (short*)alloc((size_t)512 * 512 * 2);
  short* idea  = (short*)alloc((size_t)BATCH * 512 * 2);
  unsigned short* base1 = (unsigned short*)alloc((size_t)BATCH * 2048 * 2);
  short* Wr1   = (short*)alloc((size_t)2048 * 512 * 2);
  short* W1c   = (short*)alloc((size_t)2048 * 512 * 2);
  short* Wr2i  = (short*)alloc((size_t)2048 * 512 * 2);
  short* Wr2h  = (short*)alloc((size_t)2048 * 512 * 2);
  short* Whead = (short*)alloc((size_t)16 * 512 * 2);
  float* w1r   = (float*)alloc(2048 * 4);
  float* b1r   = (float*)alloc(2048 * 4);
  float* b2r   = (float*)alloc(2048 * 4);

  prep_cvt<<<(BATCH * 512) / 256, 256, 0, stream>>>(latent, latb, BATCH * 512);
  prep_cvt<<<(512 * 512) / 256, 256, 0, stream>>>(W_unpack, Wub, 512 * 512);
  prep_reorder<<<(2048 * 512) / 256, 256, 0, stream>>>(
      W_ih1, W_hh1, b_ih1, b_hh1, W_ih2, W_hh2, b_ih2, b_hh2,
      Wr1, W1c, Wr2i, Wr2h, w1r, b1r, b2r);
  prep_whead<<<32, 256, 0, stream>>>(W_mu, W_var, W_mix, Whead);

  dim3 blk(256);
  // idea = tanh(latent @ W_unpack^T + b_unpack)  [bf16]
  gemm_fused<<<dim3(4, 32), blk, 0, stream>>>(
      latb, Wub, 512, 512, MODE_TANH, b_unpack, (void*)idea);
  // base1 = idea @ W1c^T + (b_ih1 + b_hh1)   [bf16, gate-interleaved cols]
  gemm_fused<<<dim3(16, 32), blk, 0, stream>>>(
      idea, W1c, 512, 2048, MODE_BASE, b1r, (void*)base1);

  // whole 512-step scan: 256 independent blocks, 16 rows each, no barriers
  lstm_block<<<256, 512, 0, stream>>>(
      Wr1, Wr2i, Wr2h, base1, w1r, b2r, Whead,
      b_mu, b_var, b_mix, eps, out);
}